// Round 3
// baseline (196.294 us; speedup 1.0000x reference)
//
#include <hip/hip_runtime.h>
#include <stdint.h>

#define TOPK 13
#define NEG_INF_F (-1e30f)
#define EPSF 1e-7f
#define L2EF 1.4426950408889634f
#define LN2F 0.6931471805599453f
#define MAXCAND 2048

// class_mask may arrive as bool bytes or int32; bytes 1..3 nonzero => bool bytes.
__device__ __forceinline__ int mask_at(const uint8_t* __restrict__ raw, int i) {
    bool as_u8 = (raw[1] | raw[2] | raw[3]) != 0;
    return as_u8 ? (raw[i] != 0) : (((const int*)raw)[i] != 0);
}

__device__ __forceinline__ float iou_pair(float ax1, float ay1, float ax2, float ay2,
                                          float bx1, float by1, float bx2, float by2) {
    float x1 = fmaxf(ax1, bx1), y1 = fmaxf(ay1, by1);
    float x2 = fminf(ax2, bx2), y2 = fminf(ay2, by2);
    float inter = fmaxf(x2 - x1, 0.f) * fmaxf(y2 - y1, 0.f);
    float a1 = (ax2 - ax1) * (ay2 - ay1);
    float a2 = (bx2 - bx1) * (by2 - by1);
    return inter / (a1 + a2 - inter + EPSF);
}

__device__ __forceinline__ float sigmoid_fast(float s) {
    return 1.f / (1.f + exp2f(-s * L2EF));
}
__device__ __forceinline__ float softplus_bce(float s) {   // max(s,0)+log1p(exp(-|s|))
    float t = exp2f(-fabsf(s) * L2EF);
    return fmaxf(s, 0.f) + log2f(1.f + t) * LN2F;
}

// ---- kernel 1: TAL assignment. One block per (b,m). best[b*N+n] packed:
// (float_bits(align)<<32) | (0xFFFFFFFF - m); 0 = unassigned.
__global__ __launch_bounds__(256) void assign_topk_k(
    const float* __restrict__ ps, const float* __restrict__ pb,
    const float* __restrict__ anch, const float* __restrict__ gtb,
    const int* __restrict__ gtl, const uint8_t* __restrict__ mraw,
    unsigned long long* __restrict__ best, int B, int N, int C, int M) {
    int b = blockIdx.x % B;
    int m = blockIdx.x / B;

    __shared__ float cval[MAXCAND];
    __shared__ int   cidx[MAXCAND];
    __shared__ int   scnt;
    if (threadIdx.x == 0) scnt = 0;

    int lbl = gtl[b * M + m];
    int lab = min(max(lbl, 0), C - 1);
    bool valid = (lbl >= 0) && (lbl < C) && (mask_at(mraw, b * C + lab) != 0);
    __syncthreads();

    if (valid) {
        float4 g = ((const float4*)gtb)[(size_t)b * M + m];
        const float* psb = ps + (size_t)b * N * C + lab;
        const float4* pbb = (const float4*)pb + (size_t)b * N;
        for (int n = threadIdx.x; n < N; n += 256) {
            float2 a = ((const float2*)anch)[n];
            if (a.x < g.x || a.x > g.z || a.y < g.y || a.y > g.w) continue;
            float4 p = pbb[n];
            float iou = iou_pair(p.x, p.y, p.z, p.w, g.x, g.y, g.z, g.w);
            float s = psb[(size_t)n * C];
            float sig = sigmoid_fast(s);
            float i3 = iou * iou * iou;
            float val = sig * i3 * i3;        // cls^1 * iou^6, >= 0
            int slot = atomicAdd(&scnt, 1);
            if (slot < MAXCAND) { cval[slot] = val; cidx[slot] = n; }
        }
    }
    __syncthreads();
    if (!valid || threadIdx.x >= 64) return;

    int total = min(scnt, MAXCAND);
    if (total == 0) return;
    int lane = threadIdx.x;

    float lv[TOPK];
    int   li[TOPK];
#pragma unroll
    for (int j = 0; j < TOPK; ++j) { lv[j] = NEG_INF_F; li[j] = -1; }
    for (int i = lane; i < total; i += 64) {
        float v = cval[i]; int ix = cidx[i];
        if (v > lv[TOPK - 1]) {
            bool placed = false;
#pragma unroll
            for (int j = TOPK - 1; j >= 1; --j) {
                if (!placed) {
                    if (v > lv[j - 1]) { lv[j] = lv[j - 1]; li[j] = li[j - 1]; }
                    else { lv[j] = v; li[j] = ix; placed = true; }
                }
            }
            if (!placed) { lv[0] = v; li[0] = ix; }
        }
    }

    unsigned key = 0xFFFFFFFFu - (unsigned)m;   // smaller m wins value ties
    unsigned long long* bb = best + (size_t)b * N;
    int rounds = min(total, TOPK);
    for (int p = 0; p < rounds; ++p) {
        float bv = lv[0]; int bl = lane;
        for (int off = 32; off > 0; off >>= 1) {
            float ov = __shfl_down(bv, off, 64);
            int   ol = __shfl_down(bl, off, 64);
            if (ov > bv) { bv = ov; bl = ol; }
        }
        bl = __shfl(bl, 0, 64);
        if (lane == bl) {
            unsigned long long pk =
                ((unsigned long long)__float_as_uint(lv[0]) << 32) | (unsigned long long)key;
            atomicMax(bb + li[0], pk);
#pragma unroll
            for (int j = 0; j < TOPK - 1; ++j) { lv[j] = lv[j + 1]; li[j] = li[j + 1]; }
            lv[TOPK - 1] = NEG_INF_F; li[TOPK - 1] = -1;
        }
    }
}

// ---- kernel 2: per-anchor losses (lane-pair per anchor) + fused finalize.
// partials[b*8 + {0:bce,1:cnt,2:pos,3:neg,4:miou,5:iouLoss,6:dfl}]
__global__ __launch_bounds__(256) void per_anchor_k(
    const float* __restrict__ ps, const float* __restrict__ pb,
    const float* __restrict__ anch, const float* __restrict__ strd,
    const float* __restrict__ bd, const float* __restrict__ gtb,
    const int* __restrict__ gtl, const uint8_t* __restrict__ mraw,
    const unsigned long long* __restrict__ best,
    float* __restrict__ partials, int* __restrict__ done_ctr,
    float* __restrict__ out, int B, int N, int C, int M) {
    int b = blockIdx.y;
    int half = threadIdx.x & 1;
    int n = blockIdx.x * 128 + (threadIdx.x >> 1);

    __shared__ int smask[256];
    __shared__ int s_notall;
    __shared__ float sred[4 * 8];
    __shared__ int s_last;
    if (threadIdx.x == 0) s_notall = 0;
    __syncthreads();
    for (int c = threadIdx.x; c < C && c < 256; c += 256) {
        int v = mask_at(mraw, b * C + c);
        smask[c] = v;
        if (!v) s_notall = 1;          // benign race: all writers store 1
    }
    __syncthreads();
    bool allm = (s_notall == 0);
    bool pairable = ((C & 7) == 0);

    float acc0 = 0, acc1 = 0, acc2 = 0, acc3 = 0, acc4 = 0, acc5 = 0, acc6 = 0;

    if (n < N) {
        unsigned long long pk = best[(size_t)b * N + n];
        bool fg = (pk != 0ull);
        int mg = fg ? (int)(0xFFFFFFFFu - (unsigned)(pk & 0xFFFFFFFFull)) : 0;
        int lbl = gtl[b * M + mg];
        int m_lab = min(max(lbl, 0), C - 1);

        const float* psr = ps + ((size_t)b * N + n) * C;
        float bce_sum = 0.f, smax = NEG_INF_F;

        if (pairable) {
            // lane pair splits the class scan: half h covers [h*C/2, (h+1)*C/2)
            int h4 = C >> 3;                       // float4s per half
            const float4* p4 = (const float4*)psr + half * h4;
            if (allm) {
                for (int i = 0; i < h4; ++i) {
                    float4 s4 = p4[i];
                    bce_sum += softplus_bce(s4.x) + softplus_bce(s4.y) +
                               softplus_bce(s4.z) + softplus_bce(s4.w);
                    smax = fmaxf(smax, fmaxf(fmaxf(s4.x, s4.y), fmaxf(s4.z, s4.w)));
                }
            } else {
                int cbase = half * (C >> 1);
                for (int c = 0; c < (C >> 1); ++c) {
                    float s = psr[cbase + c];
                    if (smask[cbase + c]) { bce_sum += softplus_bce(s); smax = fmaxf(smax, s); }
                }
            }
            bce_sum += __shfl_xor(bce_sum, 1, 64);
            smax = fmaxf(smax, __shfl_xor(smax, 1, 64));
        } else if (half == 0) {
            for (int c = 0; c < C; ++c) {
                float s = psr[c];
                if (allm || smask[c]) { bce_sum += softplus_bce(s); smax = fmaxf(smax, s); }
            }
        }

        if (fg) {
            float4 p = ((const float4*)pb)[(size_t)b * N + n];
            float4 g = ((const float4*)gtb)[(size_t)b * M + mg];
            float ov = iou_pair(p.x, p.y, p.z, p.w, g.x, g.y, g.z, g.w);
            // DFL: lane pair splits the 4 sides 2+2 (if pairable)
            float2 an = ((const float2*)anch)[n];
            float stv = strd[n];
            float dall[4] = { (an.x - g.x) / stv, (an.y - g.y) / stv,
                              (g.z - an.x) / stv, (g.w - an.y) / stv };
            const float* bdr = bd + ((size_t)b * N + n) * 64;
            int k0 = pairable ? half * 2 : 0;
            int k1 = pairable ? half * 2 + 2 : 4;
            float dfl = 0.f;
            for (int k = k0; k < k1; ++k) {
                float xs[16];
                float mxv = NEG_INF_F;
#pragma unroll
                for (int j = 0; j < 16; ++j) { xs[j] = bdr[k * 16 + j]; mxv = fmaxf(mxv, xs[j]); }
                float se = 0.f;
#pragma unroll
                for (int j = 0; j < 16; ++j) se += exp2f((xs[j] - mxv) * L2EF);
                float lse = mxv + log2f(se) * LN2F;
                float d = fminf(fmaxf(dall[k], 0.f), 14.99f);
                int tl = (int)d;
                int tr = min(tl + 1, 15);
                float wl = (float)tr - d;
                float xtl = bdr[k * 16 + tl];
                float xtr = bdr[k * 16 + tr];
                dfl += (lse - xtl) * wl + (lse - xtr) * (1.f - wl);
            }
            if (pairable) dfl += __shfl_xor(dfl, 1, 64);

            if (half == 0 || !pairable) {
                float slab = psr[m_lab];
                bce_sum -= fmaxf(ov, 0.1f) * slab;
                acc1 = 1.f;
                acc2 = sigmoid_fast(slab);
                acc4 = ov;
                float w1 = p.z - p.x, h1 = p.w - p.y;
                float w2 = g.z - g.x, h2 = g.w - g.y;
                float cw = fmaxf(p.z, g.z) - fminf(p.x, g.x);
                float ch = fmaxf(p.w, g.w) - fminf(p.y, g.y);
                float c2 = cw * cw + ch * ch + EPSF;
                float dx = g.x + g.z - p.x - p.z;
                float dy = g.y + g.w - p.y - p.w;
                float rho2 = (dx * dx + dy * dy) * 0.25f;
                const float PI = 3.14159265358979323846f;
                float dv = atanf(w2 / (h2 + EPSF)) - atanf(w1 / (h1 + EPSF));
                float v = (4.f / (PI * PI)) * dv * dv;
                float a = v / (v - ov + 1.f + EPSF);
                acc5 = 1.f - (ov - (rho2 / c2 + v * a));
                acc6 = dfl;
            }
        } else if (half == 0 || !pairable) {
            acc3 = sigmoid_fast(smax);
        }
        if (half == 0 || !pairable) acc0 = bce_sum;
    }

    int lane = threadIdx.x & 63, wid = threadIdx.x >> 6;
    float accs[7] = { acc0, acc1, acc2, acc3, acc4, acc5, acc6 };
#pragma unroll
    for (int j = 0; j < 7; ++j) {
        float v = accs[j];
        for (int off = 32; off > 0; off >>= 1) v += __shfl_down(v, off, 64);
        if (lane == 0) sred[wid * 8 + j] = v;
    }
    __syncthreads();
    if (threadIdx.x < 7) {
        float s = sred[0 * 8 + threadIdx.x] + sred[1 * 8 + threadIdx.x] +
                  sred[2 * 8 + threadIdx.x] + sred[3 * 8 + threadIdx.x];
        atomicAdd(&partials[b * 8 + threadIdx.x], s);
    }
    __syncthreads();   // all block's device-scope atomicAdds drained before counting
    if (threadIdx.x == 0) {
        int prev = __hip_atomic_fetch_add(done_ctr, 1, __ATOMIC_ACQ_REL,
                                          __HIP_MEMORY_SCOPE_AGENT);
        s_last = (prev == (int)(gridDim.x * gridDim.y) - 1) ? 1 : 0;
    }
    __syncthreads();
    if (s_last && threadIdx.x < 64) {
        int l = threadIdx.x;
        float tm = 0, ti = 0, td = 0, tp = 0, tneg = 0, pos = 0, neg = 0, miou = 0;
        if (l < B) {
            float vcs = 0.f;
            for (int c = 0; c < C; ++c) vcs += mask_at(mraw, l * C + c) ? 1.f : 0.f;
            float pr[7];
            for (int j = 0; j < 7; ++j)
                pr[j] = __hip_atomic_load(&partials[l * 8 + j], __ATOMIC_ACQUIRE,
                                          __HIP_MEMORY_SCOPE_AGENT);
            float cnt = pr[1];
            tm = pr[0] / ((float)N * fmaxf(vcs, 1.f));
            ti = (cnt > 0.f) ? pr[5] / fmaxf(cnt, 1.f) : 0.f;
            td = (cnt > 0.f) ? pr[6] / fmaxf(cnt * 4.f, 1.f) : 0.f;
            tp = cnt; tneg = (float)N - cnt;
            pos = pr[2]; neg = pr[3]; miou = pr[4];
        }
        for (int off = 32; off > 0; off >>= 1) {
            tm += __shfl_down(tm, off, 64);     ti += __shfl_down(ti, off, 64);
            td += __shfl_down(td, off, 64);     tp += __shfl_down(tp, off, 64);
            tneg += __shfl_down(tneg, off, 64); pos += __shfl_down(pos, off, 64);
            neg += __shfl_down(neg, off, 64);   miou += __shfl_down(miou, off, 64);
        }
        if (l == 0) {
            float Bf = (float)B;
            out[0] = (0.5f * tm + 7.5f * ti + 1.5f * td) / Bf;
            out[1] = tm / Bf;
            out[2] = ti / Bf;
            out[3] = td / Bf;
            out[4] = tp;
            out[5] = pos / fmaxf(tp, 1.f);
            out[6] = neg / fmaxf(tneg, 1.f);
            out[7] = miou / fmaxf(tp, 1.f);
        }
    }
}

extern "C" void kernel_launch(void* const* d_in, const int* in_sizes, int n_in,
                              void* d_out, int out_size, void* d_ws, size_t ws_size,
                              hipStream_t stream) {
    const float* ps   = (const float*)d_in[0];   // (B,N,C)
    const float* pb   = (const float*)d_in[1];   // (B,N,4)
    const float* anch = (const float*)d_in[2];   // (N,2)
    const float* strd = (const float*)d_in[3];   // (N,1)
    const float* bd   = (const float*)d_in[4];   // (B,N,64)
    const float* gtb  = (const float*)d_in[5];   // (B,M,4)
    const int*   gtl  = (const int*)d_in[6];     // (B,M)
    const uint8_t* cmsk = (const uint8_t*)d_in[7]; // (B,C) bool

    int N = in_sizes[2] / 2;
    int B = in_sizes[1] / (4 * N);
    int C = in_sizes[0] / (B * N);
    int M = in_sizes[6] / B;

    unsigned long long* best = (unsigned long long*)d_ws;
    size_t off = (size_t)B * N * sizeof(unsigned long long);
    off = (off + 255) & ~(size_t)255;
    float* partials = (float*)((char*)d_ws + off);
    size_t off2 = off + (size_t)B * 8 * sizeof(float);
    off2 = (off2 + 255) & ~(size_t)255;
    int* done_ctr = (int*)((char*)d_ws + off2);
    size_t total = off2 + 256;

    hipMemsetAsync(d_ws, 0, total, stream);
    assign_topk_k<<<B * M, 256, 0, stream>>>(ps, pb, anch, gtb, gtl, cmsk, best, B, N, C, M);
    dim3 gB((N + 127) / 128, B);
    per_anchor_k<<<gB, 256, 0, stream>>>(ps, pb, anch, strd, bd, gtb, gtl, cmsk, best,
                                         partials, done_ctr, (float*)d_out, B, N, C, M);
}

// Round 4
// 181.759 us; speedup vs baseline: 1.0800x; 1.0800x over previous
//
#include <hip/hip_runtime.h>
#include <stdint.h>

#define TOPK 13
#define NEG_INF_F (-1e30f)
#define EPSF 1e-7f
#define L2EF 1.4426950408889634f
#define LN2F 0.6931471805599453f
#define MAXCAND 2048

// class_mask may arrive as bool bytes or int32; bytes 1..3 nonzero => bool bytes.
__device__ __forceinline__ int mask_at(const uint8_t* __restrict__ raw, int i) {
    bool as_u8 = (raw[1] | raw[2] | raw[3]) != 0;
    return as_u8 ? (raw[i] != 0) : (((const int*)raw)[i] != 0);
}

__device__ __forceinline__ float iou_pair(float ax1, float ay1, float ax2, float ay2,
                                          float bx1, float by1, float bx2, float by2) {
    float x1 = fmaxf(ax1, bx1), y1 = fmaxf(ay1, by1);
    float x2 = fminf(ax2, bx2), y2 = fminf(ay2, by2);
    float inter = fmaxf(x2 - x1, 0.f) * fmaxf(y2 - y1, 0.f);
    float a1 = (ax2 - ax1) * (ay2 - ay1);
    float a2 = (bx2 - bx1) * (by2 - by1);
    return inter / (a1 + a2 - inter + EPSF);
}

__device__ __forceinline__ float sigmoid_fast(float s) {
    return 1.f / (1.f + exp2f(-s * L2EF));
}
__device__ __forceinline__ float softplus_bce(float s) {   // max(s,0)+log1p(exp(-|s|))
    float t = exp2f(-fabsf(s) * L2EF);
    return fmaxf(s, 0.f) + log2f(1.f + t) * LN2F;
}

// ---- kernel 1: TAL assignment. One block per (b,m). best[b*N+n] packed:
// (float_bits(align)<<32) | (0xFFFFFFFF - m); 0 = unassigned.
__global__ __launch_bounds__(256) void assign_topk_k(
    const float* __restrict__ ps, const float* __restrict__ pb,
    const float* __restrict__ anch, const float* __restrict__ gtb,
    const int* __restrict__ gtl, const uint8_t* __restrict__ mraw,
    unsigned long long* __restrict__ best, int B, int N, int C, int M) {
    int b = blockIdx.x % B;
    int m = blockIdx.x / B;

    __shared__ float cval[MAXCAND];
    __shared__ int   cidx[MAXCAND];
    __shared__ int   scnt;
    if (threadIdx.x == 0) scnt = 0;

    int lbl = gtl[b * M + m];
    int lab = min(max(lbl, 0), C - 1);
    bool valid = (lbl >= 0) && (lbl < C) && (mask_at(mraw, b * C + lab) != 0);
    __syncthreads();

    if (valid) {
        float4 g = ((const float4*)gtb)[(size_t)b * M + m];
        const float* psb = ps + (size_t)b * N * C + lab;
        const float4* pbb = (const float4*)pb + (size_t)b * N;
        for (int n = threadIdx.x; n < N; n += 256) {
            float2 a = ((const float2*)anch)[n];
            if (a.x < g.x || a.x > g.z || a.y < g.y || a.y > g.w) continue;
            float4 p = pbb[n];
            float iou = iou_pair(p.x, p.y, p.z, p.w, g.x, g.y, g.z, g.w);
            float s = psb[(size_t)n * C];
            float sig = sigmoid_fast(s);
            float i3 = iou * iou * iou;
            float val = sig * i3 * i3;        // cls^1 * iou^6, >= 0
            int slot = atomicAdd(&scnt, 1);
            if (slot < MAXCAND) { cval[slot] = val; cidx[slot] = n; }
        }
    }
    __syncthreads();
    if (!valid || threadIdx.x >= 64) return;

    int total = min(scnt, MAXCAND);
    if (total == 0) return;
    int lane = threadIdx.x;

    float lv[TOPK];
    int   li[TOPK];
#pragma unroll
    for (int j = 0; j < TOPK; ++j) { lv[j] = NEG_INF_F; li[j] = -1; }
    for (int i = lane; i < total; i += 64) {
        float v = cval[i]; int ix = cidx[i];
        if (v > lv[TOPK - 1]) {
            bool placed = false;
#pragma unroll
            for (int j = TOPK - 1; j >= 1; --j) {
                if (!placed) {
                    if (v > lv[j - 1]) { lv[j] = lv[j - 1]; li[j] = li[j - 1]; }
                    else { lv[j] = v; li[j] = ix; placed = true; }
                }
            }
            if (!placed) { lv[0] = v; li[0] = ix; }
        }
    }

    unsigned key = 0xFFFFFFFFu - (unsigned)m;   // smaller m wins value ties
    unsigned long long* bb = best + (size_t)b * N;
    int rounds = min(total, TOPK);
    for (int p = 0; p < rounds; ++p) {
        float bv = lv[0]; int bl = lane;
        for (int off = 32; off > 0; off >>= 1) {
            float ov = __shfl_down(bv, off, 64);
            int   ol = __shfl_down(bl, off, 64);
            if (ov > bv) { bv = ov; bl = ol; }
        }
        bl = __shfl(bl, 0, 64);
        if (lane == bl) {
            unsigned long long pk =
                ((unsigned long long)__float_as_uint(lv[0]) << 32) | (unsigned long long)key;
            atomicMax(bb + li[0], pk);
#pragma unroll
            for (int j = 0; j < TOPK - 1; ++j) { lv[j] = lv[j + 1]; li[j] = li[j + 1]; }
            lv[TOPK - 1] = NEG_INF_F; li[TOPK - 1] = -1;
        }
    }
}

// ---- kernel 2: per-anchor losses (1 thread = 1 anchor) + fused finalize.
// partials[b*8 + {0:bce,1:cnt,2:pos,3:neg,4:miou,5:iouLoss,6:dfl}]
__global__ __launch_bounds__(256) void per_anchor_k(
    const float* __restrict__ ps, const float* __restrict__ pb,
    const float* __restrict__ anch, const float* __restrict__ strd,
    const float* __restrict__ bd, const float* __restrict__ gtb,
    const int* __restrict__ gtl, const uint8_t* __restrict__ mraw,
    const unsigned long long* __restrict__ best,
    float* __restrict__ partials, int* __restrict__ done_ctr,
    float* __restrict__ out, int B, int N, int C, int M) {
    int b = blockIdx.y;
    int n = blockIdx.x * 256 + threadIdx.x;

    __shared__ int smask[256];
    __shared__ int s_notall;
    __shared__ float sred[4 * 8];
    __shared__ int s_last;
    if (threadIdx.x == 0) s_notall = 0;
    __syncthreads();
    for (int c = threadIdx.x; c < C && c < 256; c += 256) {
        int v = mask_at(mraw, b * C + c);
        smask[c] = v;
        if (!v) s_notall = 1;          // benign race: all writers store 1
    }
    __syncthreads();
    bool allm = (s_notall == 0);

    float acc0 = 0, acc1 = 0, acc2 = 0, acc3 = 0, acc4 = 0, acc5 = 0, acc6 = 0;

    if (n < N) {
        unsigned long long pk = best[(size_t)b * N + n];
        bool fg = (pk != 0ull);
        int mg = fg ? (int)(0xFFFFFFFFu - (unsigned)(pk & 0xFFFFFFFFull)) : 0;
        int lbl = gtl[b * M + mg];
        int m_lab = min(max(lbl, 0), C - 1);

        const float* psr = ps + ((size_t)b * N + n) * C;
        float bce_sum = 0.f, smax = NEG_INF_F;

        if (C == 80 && allm) {
            // compile-time-unrolled: 20 independent float4 loads, max MLP
            const float4* p4 = (const float4*)psr;
            float4 s4[20];
#pragma unroll
            for (int i = 0; i < 20; ++i) s4[i] = p4[i];
#pragma unroll
            for (int i = 0; i < 20; ++i) {
                bce_sum += softplus_bce(s4[i].x) + softplus_bce(s4[i].y) +
                           softplus_bce(s4[i].z) + softplus_bce(s4[i].w);
                smax = fmaxf(smax, fmaxf(fmaxf(s4[i].x, s4[i].y), fmaxf(s4[i].z, s4[i].w)));
            }
        } else if (allm) {
            int c4 = C & ~3;
            for (int c = 0; c < c4; c += 4) {
                float4 s4 = *(const float4*)(psr + c);
                bce_sum += softplus_bce(s4.x) + softplus_bce(s4.y) +
                           softplus_bce(s4.z) + softplus_bce(s4.w);
                smax = fmaxf(smax, fmaxf(fmaxf(s4.x, s4.y), fmaxf(s4.z, s4.w)));
            }
            for (int c = c4; c < C; ++c) {
                float s = psr[c];
                bce_sum += softplus_bce(s);
                smax = fmaxf(smax, s);
            }
        } else {
            for (int c = 0; c < C; ++c) {
                float s = psr[c];
                if (smask[c]) { bce_sum += softplus_bce(s); smax = fmaxf(smax, s); }
            }
        }

        acc1 = fg ? 1.f : 0.f;
        acc3 = fg ? 0.f : sigmoid_fast(smax);

        if (fg) {
            float slab = psr[m_lab];
            float4 p = ((const float4*)pb)[(size_t)b * N + n];
            float4 g = ((const float4*)gtb)[(size_t)b * M + mg];
            float ov = iou_pair(p.x, p.y, p.z, p.w, g.x, g.y, g.z, g.w);
            bce_sum -= fmaxf(ov, 0.1f) * slab;       // -ps*tgt term at c==m_lab
            acc2 = sigmoid_fast(slab);
            acc4 = ov;                                // miou_sum (iou(pb, tb=gtb))
            // CIoU(pb, gtb[mg])
            float w1 = p.z - p.x, h1 = p.w - p.y;
            float w2 = g.z - g.x, h2 = g.w - g.y;
            float cw = fmaxf(p.z, g.z) - fminf(p.x, g.x);
            float ch = fmaxf(p.w, g.w) - fminf(p.y, g.y);
            float c2 = cw * cw + ch * ch + EPSF;
            float dx = g.x + g.z - p.x - p.z;
            float dy = g.y + g.w - p.y - p.w;
            float rho2 = (dx * dx + dy * dy) * 0.25f;
            const float PI = 3.14159265358979323846f;
            float dv = atanf(w2 / (h2 + EPSF)) - atanf(w1 / (h1 + EPSF));
            float v = (4.f / (PI * PI)) * dv * dv;
            float a = v / (v - ov + 1.f + EPSF);
            acc5 = 1.f - (ov - (rho2 / c2 + v * a));
            // DFL: 4 sides, each a 16-wide logsumexp; float4-vectorized loads
            float2 an = ((const float2*)anch)[n];
            float stv = strd[n];
            float dall[4] = { (an.x - g.x) / stv, (an.y - g.y) / stv,
                              (g.z - an.x) / stv, (g.w - an.y) / stv };
            const float* bdr = bd + ((size_t)b * N + n) * 64;
            const float4* bq = (const float4*)bdr;
            float dfl = 0.f;
#pragma unroll
            for (int k = 0; k < 4; ++k) {
                float4 q0 = bq[k * 4 + 0], q1 = bq[k * 4 + 1];
                float4 q2 = bq[k * 4 + 2], q3 = bq[k * 4 + 3];
                float mxv = fmaxf(fmaxf(fmaxf(q0.x, q0.y), fmaxf(q0.z, q0.w)),
                                  fmaxf(fmaxf(q1.x, q1.y), fmaxf(q1.z, q1.w)));
                mxv = fmaxf(mxv, fmaxf(fmaxf(fmaxf(q2.x, q2.y), fmaxf(q2.z, q2.w)),
                                        fmaxf(fmaxf(q3.x, q3.y), fmaxf(q3.z, q3.w))));
                float se = exp2f((q0.x - mxv) * L2EF) + exp2f((q0.y - mxv) * L2EF) +
                           exp2f((q0.z - mxv) * L2EF) + exp2f((q0.w - mxv) * L2EF) +
                           exp2f((q1.x - mxv) * L2EF) + exp2f((q1.y - mxv) * L2EF) +
                           exp2f((q1.z - mxv) * L2EF) + exp2f((q1.w - mxv) * L2EF) +
                           exp2f((q2.x - mxv) * L2EF) + exp2f((q2.y - mxv) * L2EF) +
                           exp2f((q2.z - mxv) * L2EF) + exp2f((q2.w - mxv) * L2EF) +
                           exp2f((q3.x - mxv) * L2EF) + exp2f((q3.y - mxv) * L2EF) +
                           exp2f((q3.z - mxv) * L2EF) + exp2f((q3.w - mxv) * L2EF);
                float lse = mxv + log2f(se) * LN2F;
                float d = fminf(fmaxf(dall[k], 0.f), 14.99f);
                int tl = (int)d;
                int tr = min(tl + 1, 15);
                float wl = (float)tr - d;
                float xtl = bdr[k * 16 + tl];   // L1-hot re-read, avoids dynamic reg index
                float xtr = bdr[k * 16 + tr];
                dfl += (lse - xtl) * wl + (lse - xtr) * (1.f - wl);
            }
            acc6 = dfl;
        }
        acc0 = bce_sum;
    }

    int lane = threadIdx.x & 63, wid = threadIdx.x >> 6;
    float accs[7] = { acc0, acc1, acc2, acc3, acc4, acc5, acc6 };
#pragma unroll
    for (int j = 0; j < 7; ++j) {
        float v = accs[j];
        for (int off = 32; off > 0; off >>= 1) v += __shfl_down(v, off, 64);
        if (lane == 0) sred[wid * 8 + j] = v;
    }
    __syncthreads();
    if (threadIdx.x < 7) {
        float s = sred[0 * 8 + threadIdx.x] + sred[1 * 8 + threadIdx.x] +
                  sred[2 * 8 + threadIdx.x] + sred[3 * 8 + threadIdx.x];
        atomicAdd(&partials[b * 8 + threadIdx.x], s);
    }
    __syncthreads();   // all block's device-scope atomicAdds drained before counting
    if (threadIdx.x == 0) {
        int prev = __hip_atomic_fetch_add(done_ctr, 1, __ATOMIC_ACQ_REL,
                                          __HIP_MEMORY_SCOPE_AGENT);
        s_last = (prev == (int)(gridDim.x * gridDim.y) - 1) ? 1 : 0;
    }
    __syncthreads();
    if (s_last && threadIdx.x < 64) {
        int l = threadIdx.x;
        float tm = 0, ti = 0, td = 0, tp = 0, tneg = 0, pos = 0, neg = 0, miou = 0;
        if (l < B) {
            float vcs = 0.f;
            for (int c = 0; c < C; ++c) vcs += mask_at(mraw, l * C + c) ? 1.f : 0.f;
            float pr[7];
            for (int j = 0; j < 7; ++j)
                pr[j] = __hip_atomic_load(&partials[l * 8 + j], __ATOMIC_ACQUIRE,
                                          __HIP_MEMORY_SCOPE_AGENT);
            float cnt = pr[1];
            tm = pr[0] / ((float)N * fmaxf(vcs, 1.f));
            ti = (cnt > 0.f) ? pr[5] / fmaxf(cnt, 1.f) : 0.f;
            td = (cnt > 0.f) ? pr[6] / fmaxf(cnt * 4.f, 1.f) : 0.f;
            tp = cnt; tneg = (float)N - cnt;
            pos = pr[2]; neg = pr[3]; miou = pr[4];
        }
        for (int off = 32; off > 0; off >>= 1) {
            tm += __shfl_down(tm, off, 64);     ti += __shfl_down(ti, off, 64);
            td += __shfl_down(td, off, 64);     tp += __shfl_down(tp, off, 64);
            tneg += __shfl_down(tneg, off, 64); pos += __shfl_down(pos, off, 64);
            neg += __shfl_down(neg, off, 64);   miou += __shfl_down(miou, off, 64);
        }
        if (l == 0) {
            float Bf = (float)B;
            out[0] = (0.5f * tm + 7.5f * ti + 1.5f * td) / Bf;
            out[1] = tm / Bf;
            out[2] = ti / Bf;
            out[3] = td / Bf;
            out[4] = tp;
            out[5] = pos / fmaxf(tp, 1.f);
            out[6] = neg / fmaxf(tneg, 1.f);
            out[7] = miou / fmaxf(tp, 1.f);
        }
    }
}

extern "C" void kernel_launch(void* const* d_in, const int* in_sizes, int n_in,
                              void* d_out, int out_size, void* d_ws, size_t ws_size,
                              hipStream_t stream) {
    const float* ps   = (const float*)d_in[0];   // (B,N,C)
    const float* pb   = (const float*)d_in[1];   // (B,N,4)
    const float* anch = (const float*)d_in[2];   // (N,2)
    const float* strd = (const float*)d_in[3];   // (N,1)
    const float* bd   = (const float*)d_in[4];   // (B,N,64)
    const float* gtb  = (const float*)d_in[5];   // (B,M,4)
    const int*   gtl  = (const int*)d_in[6];     // (B,M)
    const uint8_t* cmsk = (const uint8_t*)d_in[7]; // (B,C) bool

    int N = in_sizes[2] / 2;
    int B = in_sizes[1] / (4 * N);
    int C = in_sizes[0] / (B * N);
    int M = in_sizes[6] / B;

    unsigned long long* best = (unsigned long long*)d_ws;
    size_t off = (size_t)B * N * sizeof(unsigned long long);
    off = (off + 255) & ~(size_t)255;
    float* partials = (float*)((char*)d_ws + off);
    size_t off2 = off + (size_t)B * 8 * sizeof(float);
    off2 = (off2 + 255) & ~(size_t)255;
    int* done_ctr = (int*)((char*)d_ws + off2);
    size_t total = off2 + 256;

    hipMemsetAsync(d_ws, 0, total, stream);
    assign_topk_k<<<B * M, 256, 0, stream>>>(ps, pb, anch, gtb, gtl, cmsk, best, B, N, C, M);
    dim3 gB((N + 255) / 256, B);
    per_anchor_k<<<gB, 256, 0, stream>>>(ps, pb, anch, strd, bd, gtb, gtl, cmsk, best,
                                         partials, done_ctr, (float*)d_out, B, N, C, M);
}

// Round 5
// 167.040 us; speedup vs baseline: 1.1751x; 1.0881x over previous
//
#include <hip/hip_runtime.h>
#include <stdint.h>

#define TOPK 13
#define NEG_INF_F (-1e30f)
#define EPSF 1e-7f
#define L2EF 1.4426950408889634f
#define LN2F 0.6931471805599453f
#define MAXCAND 2048

// class_mask may arrive as bool bytes or int32; bytes 1..3 nonzero => bool bytes.
__device__ __forceinline__ int mask_at(const uint8_t* __restrict__ raw, int i) {
    bool as_u8 = (raw[1] | raw[2] | raw[3]) != 0;
    return as_u8 ? (raw[i] != 0) : (((const int*)raw)[i] != 0);
}

__device__ __forceinline__ float iou_pair(float ax1, float ay1, float ax2, float ay2,
                                          float bx1, float by1, float bx2, float by2) {
    float x1 = fmaxf(ax1, bx1), y1 = fmaxf(ay1, by1);
    float x2 = fminf(ax2, bx2), y2 = fminf(ay2, by2);
    float inter = fmaxf(x2 - x1, 0.f) * fmaxf(y2 - y1, 0.f);
    float a1 = (ax2 - ax1) * (ay2 - ay1);
    float a2 = (bx2 - bx1) * (by2 - by1);
    return inter / (a1 + a2 - inter + EPSF);
}

__device__ __forceinline__ float sigmoid_fast(float s) {
    return 1.f / (1.f + exp2f(-s * L2EF));
}
__device__ __forceinline__ float softplus_bce(float s) {   // max(s,0)+log1p(exp(-|s|))
    float t = exp2f(-fabsf(s) * L2EF);
    return fmaxf(s, 0.f) + log2f(1.f + t) * LN2F;
}

// ---- kernel 1a: TAL assignment for the canonical YOLO 640px anchor grid
// (N==8400: levels 80x80/40x40/20x20, strides 8/16/32). One WAVE per (b,m):
// enumerate the rectangular inside-ranges directly (~106 candidates), per-lane
// top-13, then 13 shuffle-argmax rounds (tie-break: min anchor index, matching
// jax top_k stability). best[b*N+n] packed (float_bits(align)<<32)|(0xFFFFFFFF-m).
__global__ __launch_bounds__(64) void assign_grid_k(
    const float* __restrict__ ps, const float* __restrict__ pb,
    const float* __restrict__ gtb, const int* __restrict__ gtl,
    const uint8_t* __restrict__ mraw,
    unsigned long long* __restrict__ best, int B, int N, int C, int M) {
    int b = blockIdx.x % B;
    int m = blockIdx.x / B;

    int lbl = gtl[b * M + m];
    int lab = min(max(lbl, 0), C - 1);
    if (!((lbl >= 0) && (lbl < C) && (mask_at(mraw, b * C + lab) != 0))) return;

    float4 g = ((const float4*)gtb)[(size_t)b * M + m];

    const int   n0_[3]  = { 0, 6400, 8000 };
    const int   dim_[3] = { 80, 40, 20 };
    const float sv_[3]  = { 8.f, 16.f, 32.f };

    int ix0[3], iy0[3], ww[3], pre[4];
    pre[0] = 0;
#pragma unroll
    for (int l = 0; l < 3; ++l) {
        float s = sv_[l]; int d = dim_[l];
        int ax0 = max(0,     (int)ceilf (g.x / s - 0.5f));
        int ax1 = min(d - 1, (int)floorf(g.z / s - 0.5f));
        int ay0 = max(0,     (int)ceilf (g.y / s - 0.5f));
        int ay1 = min(d - 1, (int)floorf(g.w / s - 0.5f));
        int w = max(0, ax1 - ax0 + 1);
        int h = max(0, ay1 - ay0 + 1);
        ix0[l] = ax0; iy0[l] = ay0; ww[l] = w;
        pre[l + 1] = pre[l] + w * h;
    }
    int tot = pre[3];
    if (tot == 0) return;

    const float* psb = ps + (size_t)b * N * C + lab;
    const float4* pbb = (const float4*)pb + (size_t)b * N;
    int lane = threadIdx.x;

    float lv[TOPK];
    int   li[TOPK];
#pragma unroll
    for (int j = 0; j < TOPK; ++j) { lv[j] = NEG_INF_F; li[j] = -1; }

    for (int t = lane; t < tot; t += 64) {
        int l = (t >= pre[1]) + (t >= pre[2]);
        int r = t - pre[l];
        int w = ww[l];
        int iy = r / w, ix = r - iy * w;
        int gx = ix0[l] + ix, gy = iy0[l] + iy;
        int n = n0_[l] + gy * dim_[l] + gx;
        float4 p = pbb[n];
        float iou = iou_pair(p.x, p.y, p.z, p.w, g.x, g.y, g.z, g.w);
        float sc = psb[(size_t)n * C];
        float i3 = iou * iou * iou;
        float val = sigmoid_fast(sc) * i3 * i3;   // cls^1 * iou^6, >= 0
        if (val > lv[TOPK - 1]) {
            bool placed = false;
#pragma unroll
            for (int j = TOPK - 1; j >= 1; --j) {
                if (!placed) {
                    if (val > lv[j - 1]) { lv[j] = lv[j - 1]; li[j] = li[j - 1]; }
                    else { lv[j] = val; li[j] = n; placed = true; }
                }
            }
            if (!placed) { lv[0] = val; li[0] = n; }
        }
    }

    unsigned key = 0xFFFFFFFFu - (unsigned)m;   // smaller m wins value ties (argmax-first)
    unsigned long long* bb = best + (size_t)b * N;
    int rounds = min(tot, TOPK);
    for (int p = 0; p < rounds; ++p) {
        float bv = lv[0]; int bn = li[0];
        for (int off = 32; off > 0; off >>= 1) {
            float ov = __shfl_down(bv, off, 64);
            int   on = __shfl_down(bn, off, 64);
            // max value; tie -> min anchor index (unsigned cast sends -1 to the bottom)
            if (ov > bv || (ov == bv && (unsigned)on < (unsigned)bn)) { bv = ov; bn = on; }
        }
        bv = __shfl(bv, 0, 64);
        bn = __shfl(bn, 0, 64);
        if (bn < 0) break;
        if (li[0] == bn) {
            unsigned long long pk =
                ((unsigned long long)__float_as_uint(lv[0]) << 32) | (unsigned long long)key;
            atomicMax(bb + bn, pk);
#pragma unroll
            for (int j = 0; j < TOPK - 1; ++j) { lv[j] = lv[j + 1]; li[j] = li[j + 1]; }
            lv[TOPK - 1] = NEG_INF_F; li[TOPK - 1] = -1;
        }
    }
}

// ---- kernel 1b: generic fallback (full scan), used only when N != 8400 ----
__global__ __launch_bounds__(256) void assign_topk_k(
    const float* __restrict__ ps, const float* __restrict__ pb,
    const float* __restrict__ anch, const float* __restrict__ gtb,
    const int* __restrict__ gtl, const uint8_t* __restrict__ mraw,
    unsigned long long* __restrict__ best, int B, int N, int C, int M) {
    int b = blockIdx.x % B;
    int m = blockIdx.x / B;

    __shared__ float cval[MAXCAND];
    __shared__ int   cidx[MAXCAND];
    __shared__ int   scnt;
    if (threadIdx.x == 0) scnt = 0;

    int lbl = gtl[b * M + m];
    int lab = min(max(lbl, 0), C - 1);
    bool valid = (lbl >= 0) && (lbl < C) && (mask_at(mraw, b * C + lab) != 0);
    __syncthreads();

    if (valid) {
        float4 g = ((const float4*)gtb)[(size_t)b * M + m];
        const float* psb = ps + (size_t)b * N * C + lab;
        const float4* pbb = (const float4*)pb + (size_t)b * N;
        for (int n = threadIdx.x; n < N; n += 256) {
            float2 a = ((const float2*)anch)[n];
            if (a.x < g.x || a.x > g.z || a.y < g.y || a.y > g.w) continue;
            float4 p = pbb[n];
            float iou = iou_pair(p.x, p.y, p.z, p.w, g.x, g.y, g.z, g.w);
            float s = psb[(size_t)n * C];
            float i3 = iou * iou * iou;
            float val = sigmoid_fast(s) * i3 * i3;
            int slot = atomicAdd(&scnt, 1);
            if (slot < MAXCAND) { cval[slot] = val; cidx[slot] = n; }
        }
    }
    __syncthreads();
    if (!valid || threadIdx.x >= 64) return;

    int total = min(scnt, MAXCAND);
    if (total == 0) return;
    int lane = threadIdx.x;

    float lv[TOPK];
    int   li[TOPK];
#pragma unroll
    for (int j = 0; j < TOPK; ++j) { lv[j] = NEG_INF_F; li[j] = -1; }
    for (int i = lane; i < total; i += 64) {
        float v = cval[i]; int ix = cidx[i];
        if (v > lv[TOPK - 1]) {
            bool placed = false;
#pragma unroll
            for (int j = TOPK - 1; j >= 1; --j) {
                if (!placed) {
                    if (v > lv[j - 1]) { lv[j] = lv[j - 1]; li[j] = li[j - 1]; }
                    else { lv[j] = v; li[j] = ix; placed = true; }
                }
            }
            if (!placed) { lv[0] = v; li[0] = ix; }
        }
    }

    unsigned key = 0xFFFFFFFFu - (unsigned)m;
    unsigned long long* bb = best + (size_t)b * N;
    int rounds = min(total, TOPK);
    for (int p = 0; p < rounds; ++p) {
        float bv = lv[0]; int bn = li[0];
        for (int off = 32; off > 0; off >>= 1) {
            float ov = __shfl_down(bv, off, 64);
            int   on = __shfl_down(bn, off, 64);
            if (ov > bv || (ov == bv && (unsigned)on < (unsigned)bn)) { bv = ov; bn = on; }
        }
        bv = __shfl(bv, 0, 64);
        bn = __shfl(bn, 0, 64);
        if (bn < 0) break;
        if (li[0] == bn) {
            unsigned long long pk =
                ((unsigned long long)__float_as_uint(lv[0]) << 32) | (unsigned long long)key;
            atomicMax(bb + bn, pk);
#pragma unroll
            for (int j = 0; j < TOPK - 1; ++j) { lv[j] = lv[j + 1]; li[j] = li[j + 1]; }
            lv[TOPK - 1] = NEG_INF_F; li[TOPK - 1] = -1;
        }
    }
}

// ---- kernel 2: per-anchor losses -> per-sample partials (round-2 shape)
// partials[b*8 + {0:bce,1:cnt,2:pos,3:neg,4:miou,5:iouLoss,6:dfl}]
__global__ __launch_bounds__(256) void per_anchor_k(
    const float* __restrict__ ps, const float* __restrict__ pb,
    const float* __restrict__ anch, const float* __restrict__ strd,
    const float* __restrict__ bd, const float* __restrict__ gtb,
    const int* __restrict__ gtl, const uint8_t* __restrict__ mraw,
    const unsigned long long* __restrict__ best,
    float* __restrict__ partials, int B, int N, int C, int M) {
    int b = blockIdx.y;
    int n = blockIdx.x * 256 + threadIdx.x;

    __shared__ int smask[256];
    __shared__ int s_notall;
    __shared__ float sred[4 * 8];
    if (threadIdx.x == 0) s_notall = 0;
    __syncthreads();
    for (int c = threadIdx.x; c < C && c < 256; c += 256) {
        int v = mask_at(mraw, b * C + c);
        smask[c] = v;
        if (!v) s_notall = 1;          // benign race: all writers store 1
    }
    __syncthreads();
    bool allm = (s_notall == 0);

    float acc0 = 0, acc1 = 0, acc2 = 0, acc3 = 0, acc4 = 0, acc5 = 0, acc6 = 0;

    if (n < N) {
        unsigned long long pk = best[(size_t)b * N + n];
        bool fg = (pk != 0ull);
        int mg = fg ? (int)(0xFFFFFFFFu - (unsigned)(pk & 0xFFFFFFFFull)) : 0;
        int lbl = gtl[b * M + mg];
        int m_lab = min(max(lbl, 0), C - 1);

        const float* psr = ps + ((size_t)b * N + n) * C;
        float bce_sum = 0.f, smax = NEG_INF_F;
        if (allm) {
            int c4 = C & ~3;
            for (int c = 0; c < c4; c += 4) {
                float4 s4 = *(const float4*)(psr + c);
                bce_sum += softplus_bce(s4.x) + softplus_bce(s4.y) +
                           softplus_bce(s4.z) + softplus_bce(s4.w);
                smax = fmaxf(smax, fmaxf(fmaxf(s4.x, s4.y), fmaxf(s4.z, s4.w)));
            }
            for (int c = c4; c < C; ++c) {
                float s = psr[c];
                bce_sum += softplus_bce(s);
                smax = fmaxf(smax, s);
            }
        } else {
            for (int c = 0; c < C; ++c) {
                float s = psr[c];
                if (smask[c]) { bce_sum += softplus_bce(s); smax = fmaxf(smax, s); }
            }
        }

        float fgf = fg ? 1.f : 0.f;
        acc1 = fgf;
        acc3 = fg ? 0.f : sigmoid_fast(smax);

        if (fg) {
            float slab = psr[m_lab];
            float4 p = ((const float4*)pb)[(size_t)b * N + n];
            float4 g = ((const float4*)gtb)[(size_t)b * M + mg];
            float ov = iou_pair(p.x, p.y, p.z, p.w, g.x, g.y, g.z, g.w);
            bce_sum -= fmaxf(ov, 0.1f) * slab;       // -ps*tgt term at c==m_lab
            acc2 = sigmoid_fast(slab);
            acc4 = ov;                                // miou_sum (iou(pb, tb=gtb))
            // CIoU(pb, gtb[mg])
            float w1 = p.z - p.x, h1 = p.w - p.y;
            float w2 = g.z - g.x, h2 = g.w - g.y;
            float cw = fmaxf(p.z, g.z) - fminf(p.x, g.x);
            float ch = fmaxf(p.w, g.w) - fminf(p.y, g.y);
            float c2 = cw * cw + ch * ch + EPSF;
            float dx = g.x + g.z - p.x - p.z;
            float dy = g.y + g.w - p.y - p.w;
            float rho2 = (dx * dx + dy * dy) * 0.25f;
            const float PI = 3.14159265358979323846f;
            float dv = atanf(w2 / (h2 + EPSF)) - atanf(w1 / (h1 + EPSF));
            float v = (4.f / (PI * PI)) * dv * dv;
            float a = v / (v - ov + 1.f + EPSF);
            acc5 = 1.f - (ov - (rho2 / c2 + v * a));
            // DFL
            float2 an = ((const float2*)anch)[n];
            float stv = strd[n];
            float dall[4] = { (an.x - g.x) / stv, (an.y - g.y) / stv,
                              (g.z - an.x) / stv, (g.w - an.y) / stv };
            const float* bdr = bd + ((size_t)b * N + n) * 64;
            float dfl = 0.f;
            for (int k = 0; k < 4; ++k) {
                float xs[16];
                float mxv = NEG_INF_F;
#pragma unroll
                for (int j = 0; j < 16; ++j) { xs[j] = bdr[k * 16 + j]; mxv = fmaxf(mxv, xs[j]); }
                float se = 0.f;
#pragma unroll
                for (int j = 0; j < 16; ++j) se += exp2f((xs[j] - mxv) * L2EF);
                float lse = mxv + log2f(se) * LN2F;
                float d = fminf(fmaxf(dall[k], 0.f), 14.99f);
                int tl = (int)d;
                int tr = min(tl + 1, 15);
                float wl = (float)tr - d;
                float xtl = bdr[k * 16 + tl];   // L1-hot re-read, avoids dynamic reg index
                float xtr = bdr[k * 16 + tr];
                dfl += (lse - xtl) * wl + (lse - xtr) * (1.f - wl);
            }
            acc6 = dfl;
        }
        acc0 = bce_sum;
    }

    int lane = threadIdx.x & 63, wid = threadIdx.x >> 6;
    float accs[7] = { acc0, acc1, acc2, acc3, acc4, acc5, acc6 };
#pragma unroll
    for (int j = 0; j < 7; ++j) {
        float v = accs[j];
        for (int off = 32; off > 0; off >>= 1) v += __shfl_down(v, off, 64);
        if (lane == 0) sred[wid * 8 + j] = v;
    }
    __syncthreads();
    if (threadIdx.x < 7) {
        float s = sred[0 * 8 + threadIdx.x] + sred[1 * 8 + threadIdx.x] +
                  sred[2 * 8 + threadIdx.x] + sred[3 * 8 + threadIdx.x];
        atomicAdd(&partials[b * 8 + threadIdx.x], s);
    }
}

// ---- kernel 3: finalize (one wave; lane b handles sample b, shuffle-reduce)
__global__ void finalize_k(const float* __restrict__ partials, const uint8_t* __restrict__ mraw,
                           float* __restrict__ out, int B, int N, int C) {
    int lane = threadIdx.x;
    float tm = 0, ti = 0, td = 0, tp = 0, tneg = 0, pos = 0, neg = 0, miou = 0;
    if (lane < B) {
        float vcs = 0.f;
        for (int c = 0; c < C; ++c) vcs += mask_at(mraw, lane * C + c) ? 1.f : 0.f;
        const float* pr = partials + lane * 8;
        float cnt = pr[1];
        tm = pr[0] / ((float)N * fmaxf(vcs, 1.f));
        ti = (cnt > 0.f) ? pr[5] / fmaxf(cnt, 1.f) : 0.f;
        td = (cnt > 0.f) ? pr[6] / fmaxf(cnt * 4.f, 1.f) : 0.f;
        tp = cnt; tneg = (float)N - cnt;
        pos = pr[2]; neg = pr[3]; miou = pr[4];
    }
    for (int off = 32; off > 0; off >>= 1) {
        tm += __shfl_down(tm, off, 64);   ti += __shfl_down(ti, off, 64);
        td += __shfl_down(td, off, 64);   tp += __shfl_down(tp, off, 64);
        tneg += __shfl_down(tneg, off, 64); pos += __shfl_down(pos, off, 64);
        neg += __shfl_down(neg, off, 64); miou += __shfl_down(miou, off, 64);
    }
    if (lane == 0) {
        float Bf = (float)B;
        out[0] = (0.5f * tm + 7.5f * ti + 1.5f * td) / Bf;
        out[1] = tm / Bf;
        out[2] = ti / Bf;
        out[3] = td / Bf;
        out[4] = tp;
        out[5] = pos / fmaxf(tp, 1.f);
        out[6] = neg / fmaxf(tneg, 1.f);
        out[7] = miou / fmaxf(tp, 1.f);
    }
}

extern "C" void kernel_launch(void* const* d_in, const int* in_sizes, int n_in,
                              void* d_out, int out_size, void* d_ws, size_t ws_size,
                              hipStream_t stream) {
    const float* ps   = (const float*)d_in[0];   // (B,N,C)
    const float* pb   = (const float*)d_in[1];   // (B,N,4)
    const float* anch = (const float*)d_in[2];   // (N,2)
    const float* strd = (const float*)d_in[3];   // (N,1)
    const float* bd   = (const float*)d_in[4];   // (B,N,64)
    const float* gtb  = (const float*)d_in[5];   // (B,M,4)
    const int*   gtl  = (const int*)d_in[6];     // (B,M)
    const uint8_t* cmsk = (const uint8_t*)d_in[7]; // (B,C) bool

    int N = in_sizes[2] / 2;
    int B = in_sizes[1] / (4 * N);
    int C = in_sizes[0] / (B * N);
    int M = in_sizes[6] / B;

    unsigned long long* best = (unsigned long long*)d_ws;
    size_t off = (size_t)B * N * sizeof(unsigned long long);
    off = (off + 255) & ~(size_t)255;
    float* partials = (float*)((char*)d_ws + off);
    size_t total = off + (size_t)B * 8 * sizeof(float);

    hipMemsetAsync(d_ws, 0, total, stream);
    if (N == 8400) {
        assign_grid_k<<<B * M, 64, 0, stream>>>(ps, pb, gtb, gtl, cmsk, best, B, N, C, M);
    } else {
        assign_topk_k<<<B * M, 256, 0, stream>>>(ps, pb, anch, gtb, gtl, cmsk, best, B, N, C, M);
    }
    dim3 gB((N + 255) / 256, B);
    per_anchor_k<<<gB, 256, 0, stream>>>(ps, pb, anch, strd, bd, gtb, gtl, cmsk, best,
                                         partials, B, N, C, M);
    finalize_k<<<1, 64, 0, stream>>>(partials, cmsk, (float*)d_out, B, N, C);
}

// Round 6
// 162.543 us; speedup vs baseline: 1.2076x; 1.0277x over previous
//
#include <hip/hip_runtime.h>
#include <stdint.h>

#define TOPK 13
#define NEG_INF_F (-1e30f)
#define EPSF 1e-7f
#define L2EF 1.4426950408889634f
#define LN2F 0.6931471805599453f
#define MAXCAND 2048

// class_mask may arrive as bool bytes or int32; bytes 1..3 nonzero => bool bytes.
__device__ __forceinline__ int mask_at(const uint8_t* __restrict__ raw, int i) {
    bool as_u8 = (raw[1] | raw[2] | raw[3]) != 0;
    return as_u8 ? (raw[i] != 0) : (((const int*)raw)[i] != 0);
}

__device__ __forceinline__ float iou_pair(float ax1, float ay1, float ax2, float ay2,
                                          float bx1, float by1, float bx2, float by2) {
    float x1 = fmaxf(ax1, bx1), y1 = fmaxf(ay1, by1);
    float x2 = fminf(ax2, bx2), y2 = fminf(ay2, by2);
    float inter = fmaxf(x2 - x1, 0.f) * fmaxf(y2 - y1, 0.f);
    float a1 = (ax2 - ax1) * (ay2 - ay1);
    float a2 = (bx2 - bx1) * (by2 - by1);
    return inter / (a1 + a2 - inter + EPSF);
}

__device__ __forceinline__ float sigmoid_fast(float s) {
    return 1.f / (1.f + exp2f(-s * L2EF));
}
__device__ __forceinline__ float softplus_bce(float s) {   // max(s,0)+log1p(exp(-|s|))
    float t = exp2f(-fabsf(s) * L2EF);
    return fmaxf(s, 0.f) + log2f(1.f + t) * LN2F;
}

// ---- kernel 1a: TAL assignment for the canonical YOLO 640px anchor grid
// (N==8400: levels 80x80/40x40/20x20, strides 8/16/32). One WAVE per (b,m):
// enumerate rectangular inside-ranges directly (~106 candidates), per-lane
// top-13, then 13 shuffle-argmax rounds (tie-break: min anchor index).
__global__ __launch_bounds__(64) void assign_grid_k(
    const float* __restrict__ ps, const float* __restrict__ pb,
    const float* __restrict__ gtb, const int* __restrict__ gtl,
    const uint8_t* __restrict__ mraw,
    unsigned long long* __restrict__ best, int B, int N, int C, int M) {
    int b = blockIdx.x % B;
    int m = blockIdx.x / B;

    int lbl = gtl[b * M + m];
    int lab = min(max(lbl, 0), C - 1);
    if (!((lbl >= 0) && (lbl < C) && (mask_at(mraw, b * C + lab) != 0))) return;

    float4 g = ((const float4*)gtb)[(size_t)b * M + m];

    const int   n0_[3]  = { 0, 6400, 8000 };
    const int   dim_[3] = { 80, 40, 20 };
    const float sv_[3]  = { 8.f, 16.f, 32.f };

    int ix0[3], iy0[3], ww[3], pre[4];
    pre[0] = 0;
#pragma unroll
    for (int l = 0; l < 3; ++l) {
        float s = sv_[l]; int d = dim_[l];
        int ax0 = max(0,     (int)ceilf (g.x / s - 0.5f));
        int ax1 = min(d - 1, (int)floorf(g.z / s - 0.5f));
        int ay0 = max(0,     (int)ceilf (g.y / s - 0.5f));
        int ay1 = min(d - 1, (int)floorf(g.w / s - 0.5f));
        int w = max(0, ax1 - ax0 + 1);
        int h = max(0, ay1 - ay0 + 1);
        ix0[l] = ax0; iy0[l] = ay0; ww[l] = w;
        pre[l + 1] = pre[l] + w * h;
    }
    int tot = pre[3];
    if (tot == 0) return;

    const float* psb = ps + (size_t)b * N * C + lab;
    const float4* pbb = (const float4*)pb + (size_t)b * N;
    int lane = threadIdx.x;

    float lv[TOPK];
    int   li[TOPK];
#pragma unroll
    for (int j = 0; j < TOPK; ++j) { lv[j] = NEG_INF_F; li[j] = -1; }

    for (int t = lane; t < tot; t += 64) {
        int l = (t >= pre[1]) + (t >= pre[2]);
        int r = t - pre[l];
        int w = ww[l];
        int iy = r / w, ix = r - iy * w;
        int gx = ix0[l] + ix, gy = iy0[l] + iy;
        int n = n0_[l] + gy * dim_[l] + gx;
        float4 p = pbb[n];
        float iou = iou_pair(p.x, p.y, p.z, p.w, g.x, g.y, g.z, g.w);
        float sc = psb[(size_t)n * C];
        float i3 = iou * iou * iou;
        float val = sigmoid_fast(sc) * i3 * i3;   // cls^1 * iou^6, >= 0
        if (val > lv[TOPK - 1]) {
            bool placed = false;
#pragma unroll
            for (int j = TOPK - 1; j >= 1; --j) {
                if (!placed) {
                    if (val > lv[j - 1]) { lv[j] = lv[j - 1]; li[j] = li[j - 1]; }
                    else { lv[j] = val; li[j] = n; placed = true; }
                }
            }
            if (!placed) { lv[0] = val; li[0] = n; }
        }
    }

    unsigned key = 0xFFFFFFFFu - (unsigned)m;   // smaller m wins value ties (argmax-first)
    unsigned long long* bb = best + (size_t)b * N;
    int rounds = min(tot, TOPK);
    for (int p = 0; p < rounds; ++p) {
        float bv = lv[0]; int bn = li[0];
        for (int off = 32; off > 0; off >>= 1) {
            float ov = __shfl_down(bv, off, 64);
            int   on = __shfl_down(bn, off, 64);
            if (ov > bv || (ov == bv && (unsigned)on < (unsigned)bn)) { bv = ov; bn = on; }
        }
        bv = __shfl(bv, 0, 64);
        bn = __shfl(bn, 0, 64);
        if (bn < 0) break;
        if (li[0] == bn) {
            unsigned long long pk =
                ((unsigned long long)__float_as_uint(lv[0]) << 32) | (unsigned long long)key;
            atomicMax(bb + bn, pk);
#pragma unroll
            for (int j = 0; j < TOPK - 1; ++j) { lv[j] = lv[j + 1]; li[j] = li[j + 1]; }
            lv[TOPK - 1] = NEG_INF_F; li[TOPK - 1] = -1;
        }
    }
}

// ---- kernel 1b: generic fallback (full scan), used only when N != 8400 ----
__global__ __launch_bounds__(256) void assign_topk_k(
    const float* __restrict__ ps, const float* __restrict__ pb,
    const float* __restrict__ anch, const float* __restrict__ gtb,
    const int* __restrict__ gtl, const uint8_t* __restrict__ mraw,
    unsigned long long* __restrict__ best, int B, int N, int C, int M) {
    int b = blockIdx.x % B;
    int m = blockIdx.x / B;

    __shared__ float cval[MAXCAND];
    __shared__ int   cidx[MAXCAND];
    __shared__ int   scnt;
    if (threadIdx.x == 0) scnt = 0;

    int lbl = gtl[b * M + m];
    int lab = min(max(lbl, 0), C - 1);
    bool valid = (lbl >= 0) && (lbl < C) && (mask_at(mraw, b * C + lab) != 0);
    __syncthreads();

    if (valid) {
        float4 g = ((const float4*)gtb)[(size_t)b * M + m];
        const float* psb = ps + (size_t)b * N * C + lab;
        const float4* pbb = (const float4*)pb + (size_t)b * N;
        for (int n = threadIdx.x; n < N; n += 256) {
            float2 a = ((const float2*)anch)[n];
            if (a.x < g.x || a.x > g.z || a.y < g.y || a.y > g.w) continue;
            float4 p = pbb[n];
            float iou = iou_pair(p.x, p.y, p.z, p.w, g.x, g.y, g.z, g.w);
            float s = psb[(size_t)n * C];
            float i3 = iou * iou * iou;
            float val = sigmoid_fast(s) * i3 * i3;
            int slot = atomicAdd(&scnt, 1);
            if (slot < MAXCAND) { cval[slot] = val; cidx[slot] = n; }
        }
    }
    __syncthreads();
    if (!valid || threadIdx.x >= 64) return;

    int total = min(scnt, MAXCAND);
    if (total == 0) return;
    int lane = threadIdx.x;

    float lv[TOPK];
    int   li[TOPK];
#pragma unroll
    for (int j = 0; j < TOPK; ++j) { lv[j] = NEG_INF_F; li[j] = -1; }
    for (int i = lane; i < total; i += 64) {
        float v = cval[i]; int ix = cidx[i];
        if (v > lv[TOPK - 1]) {
            bool placed = false;
#pragma unroll
            for (int j = TOPK - 1; j >= 1; --j) {
                if (!placed) {
                    if (v > lv[j - 1]) { lv[j] = lv[j - 1]; li[j] = li[j - 1]; }
                    else { lv[j] = v; li[j] = ix; placed = true; }
                }
            }
            if (!placed) { lv[0] = v; li[0] = ix; }
        }
    }

    unsigned key = 0xFFFFFFFFu - (unsigned)m;
    unsigned long long* bb = best + (size_t)b * N;
    int rounds = min(total, TOPK);
    for (int p = 0; p < rounds; ++p) {
        float bv = lv[0]; int bn = li[0];
        for (int off = 32; off > 0; off >>= 1) {
            float ov = __shfl_down(bv, off, 64);
            int   on = __shfl_down(bn, off, 64);
            if (ov > bv || (ov == bv && (unsigned)on < (unsigned)bn)) { bv = ov; bn = on; }
        }
        bv = __shfl(bv, 0, 64);
        bn = __shfl(bn, 0, 64);
        if (bn < 0) break;
        if (li[0] == bn) {
            unsigned long long pk =
                ((unsigned long long)__float_as_uint(lv[0]) << 32) | (unsigned long long)key;
            atomicMax(bb + bn, pk);
#pragma unroll
            for (int j = 0; j < TOPK - 1; ++j) { lv[j] = lv[j + 1]; li[j] = li[j + 1]; }
            lv[TOPK - 1] = NEG_INF_F; li[TOPK - 1] = -1;
        }
    }
}

// ---- kernel 2: per-anchor losses -> per-sample partials.
// __launch_bounds__(256,1): occupancy is grid-limited (~2 waves/SIMD), so lift the
// VGPR cap and let the 20xfloat4 ps-row burst (and 16xfloat4 bd burst) stay in flight.
__global__ __launch_bounds__(256, 1) void per_anchor_k(
    const float* __restrict__ ps, const float* __restrict__ pb,
    const float* __restrict__ anch, const float* __restrict__ strd,
    const float* __restrict__ bd, const float* __restrict__ gtb,
    const int* __restrict__ gtl, const uint8_t* __restrict__ mraw,
    const unsigned long long* __restrict__ best,
    float* __restrict__ partials, int B, int N, int C, int M) {
    int b = blockIdx.y;
    int n = blockIdx.x * 256 + threadIdx.x;

    __shared__ int smask[256];
    __shared__ int s_notall;
    __shared__ float sred[4 * 8];
    if (threadIdx.x == 0) s_notall = 0;
    __syncthreads();
    for (int c = threadIdx.x; c < C && c < 256; c += 256) {
        int v = mask_at(mraw, b * C + c);
        smask[c] = v;
        if (!v) s_notall = 1;          // benign race: all writers store 1
    }
    __syncthreads();
    bool allm = (s_notall == 0);

    float acc0 = 0, acc1 = 0, acc2 = 0, acc3 = 0, acc4 = 0, acc5 = 0, acc6 = 0;

    if (n < N) {
        unsigned long long pk = best[(size_t)b * N + n];
        bool fg = (pk != 0ull);
        int mg = fg ? (int)(0xFFFFFFFFu - (unsigned)(pk & 0xFFFFFFFFull)) : 0;
        int lbl = gtl[b * M + mg];
        int m_lab = min(max(lbl, 0), C - 1);

        const float* psr = ps + ((size_t)b * N + n) * C;
        float bce_sum = 0.f, smax = NEG_INF_F;

        if (C == 80 && allm) {
            // burst: 20 independent dwordx4 loads issued before first use
            const float4* p4 = (const float4*)psr;
            float4 s4[20];
#pragma unroll
            for (int i = 0; i < 20; ++i) s4[i] = p4[i];
#pragma unroll
            for (int i = 0; i < 20; ++i) {
                bce_sum += softplus_bce(s4[i].x) + softplus_bce(s4[i].y) +
                           softplus_bce(s4[i].z) + softplus_bce(s4[i].w);
                smax = fmaxf(smax, fmaxf(fmaxf(s4[i].x, s4[i].y), fmaxf(s4[i].z, s4[i].w)));
            }
        } else if (allm) {
            int c4 = C & ~3;
            for (int c = 0; c < c4; c += 4) {
                float4 s4 = *(const float4*)(psr + c);
                bce_sum += softplus_bce(s4.x) + softplus_bce(s4.y) +
                           softplus_bce(s4.z) + softplus_bce(s4.w);
                smax = fmaxf(smax, fmaxf(fmaxf(s4.x, s4.y), fmaxf(s4.z, s4.w)));
            }
            for (int c = c4; c < C; ++c) {
                float s = psr[c];
                bce_sum += softplus_bce(s);
                smax = fmaxf(smax, s);
            }
        } else {
            for (int c = 0; c < C; ++c) {
                float s = psr[c];
                if (smask[c]) { bce_sum += softplus_bce(s); smax = fmaxf(smax, s); }
            }
        }

        acc1 = fg ? 1.f : 0.f;
        acc3 = fg ? 0.f : sigmoid_fast(smax);

        if (fg) {
            // burst the fg-path inputs first: bd row (16x dwordx4), pb, gtb, anchor, stride
            const float* bdr = bd + ((size_t)b * N + n) * 64;
            const float4* bq4 = (const float4*)bdr;
            float4 bq[16];
#pragma unroll
            for (int i = 0; i < 16; ++i) bq[i] = bq4[i];
            float4 p = ((const float4*)pb)[(size_t)b * N + n];
            float4 g = ((const float4*)gtb)[(size_t)b * M + mg];
            float2 an = ((const float2*)anch)[n];
            float stv = strd[n];
            float slab = psr[m_lab];                 // L1-hot (row just streamed)

            float ov = iou_pair(p.x, p.y, p.z, p.w, g.x, g.y, g.z, g.w);
            bce_sum -= fmaxf(ov, 0.1f) * slab;       // -ps*tgt term at c==m_lab
            acc2 = sigmoid_fast(slab);
            acc4 = ov;                                // miou_sum (iou(pb, tb=gtb))
            // CIoU(pb, gtb[mg])
            float w1 = p.z - p.x, h1 = p.w - p.y;
            float w2 = g.z - g.x, h2 = g.w - g.y;
            float cw = fmaxf(p.z, g.z) - fminf(p.x, g.x);
            float ch = fmaxf(p.w, g.w) - fminf(p.y, g.y);
            float c2 = cw * cw + ch * ch + EPSF;
            float dx = g.x + g.z - p.x - p.z;
            float dy = g.y + g.w - p.y - p.w;
            float rho2 = (dx * dx + dy * dy) * 0.25f;
            const float PI = 3.14159265358979323846f;
            float dv = atanf(w2 / (h2 + EPSF)) - atanf(w1 / (h1 + EPSF));
            float v = (4.f / (PI * PI)) * dv * dv;
            float a = v / (v - ov + 1.f + EPSF);
            acc5 = 1.f - (ov - (rho2 / c2 + v * a));
            // DFL from the register-resident bd row
            float dall[4] = { (an.x - g.x) / stv, (an.y - g.y) / stv,
                              (g.z - an.x) / stv, (g.w - an.y) / stv };
            float dfl = 0.f;
#pragma unroll
            for (int k = 0; k < 4; ++k) {
                float4 q0 = bq[k * 4 + 0], q1 = bq[k * 4 + 1];
                float4 q2 = bq[k * 4 + 2], q3 = bq[k * 4 + 3];
                float mxv = fmaxf(fmaxf(fmaxf(q0.x, q0.y), fmaxf(q0.z, q0.w)),
                                  fmaxf(fmaxf(q1.x, q1.y), fmaxf(q1.z, q1.w)));
                mxv = fmaxf(mxv, fmaxf(fmaxf(fmaxf(q2.x, q2.y), fmaxf(q2.z, q2.w)),
                                        fmaxf(fmaxf(q3.x, q3.y), fmaxf(q3.z, q3.w))));
                float se = exp2f((q0.x - mxv) * L2EF) + exp2f((q0.y - mxv) * L2EF) +
                           exp2f((q0.z - mxv) * L2EF) + exp2f((q0.w - mxv) * L2EF) +
                           exp2f((q1.x - mxv) * L2EF) + exp2f((q1.y - mxv) * L2EF) +
                           exp2f((q1.z - mxv) * L2EF) + exp2f((q1.w - mxv) * L2EF) +
                           exp2f((q2.x - mxv) * L2EF) + exp2f((q2.y - mxv) * L2EF) +
                           exp2f((q2.z - mxv) * L2EF) + exp2f((q2.w - mxv) * L2EF) +
                           exp2f((q3.x - mxv) * L2EF) + exp2f((q3.y - mxv) * L2EF) +
                           exp2f((q3.z - mxv) * L2EF) + exp2f((q3.w - mxv) * L2EF);
                float lse = mxv + log2f(se) * LN2F;
                float d = fminf(fmaxf(dall[k], 0.f), 14.99f);
                int tl = (int)d;
                int tr = min(tl + 1, 15);
                float wl = (float)tr - d;
                float xtl = bdr[k * 16 + tl];   // L1-hot re-read, avoids dynamic reg index
                float xtr = bdr[k * 16 + tr];
                dfl += (lse - xtl) * wl + (lse - xtr) * (1.f - wl);
            }
            acc6 = dfl;
        }
        acc0 = bce_sum;
    }

    int lane = threadIdx.x & 63, wid = threadIdx.x >> 6;
    float accs[7] = { acc0, acc1, acc2, acc3, acc4, acc5, acc6 };
#pragma unroll
    for (int j = 0; j < 7; ++j) {
        float v = accs[j];
        for (int off = 32; off > 0; off >>= 1) v += __shfl_down(v, off, 64);
        if (lane == 0) sred[wid * 8 + j] = v;
    }
    __syncthreads();
    if (threadIdx.x < 7) {
        float s = sred[0 * 8 + threadIdx.x] + sred[1 * 8 + threadIdx.x] +
                  sred[2 * 8 + threadIdx.x] + sred[3 * 8 + threadIdx.x];
        atomicAdd(&partials[b * 8 + threadIdx.x], s);
    }
}

// ---- kernel 3: finalize (one wave; lane b handles sample b, shuffle-reduce)
__global__ void finalize_k(const float* __restrict__ partials, const uint8_t* __restrict__ mraw,
                           float* __restrict__ out, int B, int N, int C) {
    int lane = threadIdx.x;
    float tm = 0, ti = 0, td = 0, tp = 0, tneg = 0, pos = 0, neg = 0, miou = 0;
    if (lane < B) {
        float vcs = 0.f;
        for (int c = 0; c < C; ++c) vcs += mask_at(mraw, lane * C + c) ? 1.f : 0.f;
        const float* pr = partials + lane * 8;
        float cnt = pr[1];
        tm = pr[0] / ((float)N * fmaxf(vcs, 1.f));
        ti = (cnt > 0.f) ? pr[5] / fmaxf(cnt, 1.f) : 0.f;
        td = (cnt > 0.f) ? pr[6] / fmaxf(cnt * 4.f, 1.f) : 0.f;
        tp = cnt; tneg = (float)N - cnt;
        pos = pr[2]; neg = pr[3]; miou = pr[4];
    }
    for (int off = 32; off > 0; off >>= 1) {
        tm += __shfl_down(tm, off, 64);   ti += __shfl_down(ti, off, 64);
        td += __shfl_down(td, off, 64);   tp += __shfl_down(tp, off, 64);
        tneg += __shfl_down(tneg, off, 64); pos += __shfl_down(pos, off, 64);
        neg += __shfl_down(neg, off, 64); miou += __shfl_down(miou, off, 64);
    }
    if (lane == 0) {
        float Bf = (float)B;
        out[0] = (0.5f * tm + 7.5f * ti + 1.5f * td) / Bf;
        out[1] = tm / Bf;
        out[2] = ti / Bf;
        out[3] = td / Bf;
        out[4] = tp;
        out[5] = pos / fmaxf(tp, 1.f);
        out[6] = neg / fmaxf(tneg, 1.f);
        out[7] = miou / fmaxf(tp, 1.f);
    }
}

extern "C" void kernel_launch(void* const* d_in, const int* in_sizes, int n_in,
                              void* d_out, int out_size, void* d_ws, size_t ws_size,
                              hipStream_t stream) {
    const float* ps   = (const float*)d_in[0];   // (B,N,C)
    const float* pb   = (const float*)d_in[1];   // (B,N,4)
    const float* anch = (const float*)d_in[2];   // (N,2)
    const float* strd = (const float*)d_in[3];   // (N,1)
    const float* bd   = (const float*)d_in[4];   // (B,N,64)
    const float* gtb  = (const float*)d_in[5];   // (B,M,4)
    const int*   gtl  = (const int*)d_in[6];     // (B,M)
    const uint8_t* cmsk = (const uint8_t*)d_in[7]; // (B,C) bool

    int N = in_sizes[2] / 2;
    int B = in_sizes[1] / (4 * N);
    int C = in_sizes[0] / (B * N);
    int M = in_sizes[6] / B;

    unsigned long long* best = (unsigned long long*)d_ws;
    size_t off = (size_t)B * N * sizeof(unsigned long long);
    off = (off + 255) & ~(size_t)255;
    float* partials = (float*)((char*)d_ws + off);
    size_t total = off + (size_t)B * 8 * sizeof(float);

    hipMemsetAsync(d_ws, 0, total, stream);
    if (N == 8400) {
        assign_grid_k<<<B * M, 64, 0, stream>>>(ps, pb, gtb, gtl, cmsk, best, B, N, C, M);
    } else {
        assign_topk_k<<<B * M, 256, 0, stream>>>(ps, pb, anch, gtb, gtl, cmsk, best, B, N, C, M);
    }
    dim3 gB((N + 255) / 256, B);
    per_anchor_k<<<gB, 256, 0, stream>>>(ps, pb, anch, strd, bd, gtb, gtl, cmsk, best,
                                         partials, B, N, C, M);
    finalize_k<<<1, 64, 0, stream>>>(partials, cmsk, (float*)d_out, B, N, C);
}